// Round 12
// baseline (59.270 us; speedup 1.0000x reference)
//
#include <hip/hip_runtime.h>
#include <hip/hip_bf16.h>
#include <math.h>

typedef unsigned int u32;
typedef __fp16 f16x2 __attribute__((ext_vector_type(2)));
typedef u32 u32x4 __attribute__((ext_vector_type(4)));

#define NB    192
#define NC    32
#define TFUT  27
#define NPAIR 96                 // k_recur blocks; block handles batches b, b+96
#define BLOB_F_OFF (NB * 64)     // float offset of packed-weight blob inside ws

#if __has_builtin(__builtin_amdgcn_rcpf)
#define RCPF(x) __builtin_amdgcn_rcpf(x)
#else
#define RCPF(x) (1.0f / (x))
#endif
#if __has_builtin(__builtin_amdgcn_sqrtf)
#define SQRTF(x) __builtin_amdgcn_sqrtf(x)
#else
#define SQRTF(x) sqrtf(x)
#endif
#if __has_builtin(__builtin_amdgcn_exp2f)
#define EXP2F(x) __builtin_amdgcn_exp2f(x)
#else
#define EXP2F(x) exp2f(x)
#endif
#if __has_builtin(__builtin_amdgcn_logf)
#define LOG2F(x) __builtin_amdgcn_logf(x)
#else
#define LOG2F(x) log2f(x)
#endif

// compiler-level ordering for intra-wave LDS communication (free at runtime;
// HW DS pipe is in-order within a wave).
#define LDS_FENCE() asm volatile("" ::: "memory")

__device__ __forceinline__ u32 pk16(float lo, float hi) {
    auto v = __builtin_amdgcn_cvt_pkrtz(lo, hi);
    return __builtin_bit_cast(u32, v);
}
__device__ __forceinline__ float fdot2pk(u32 a, u32 b, float c) {
#if __has_builtin(__builtin_amdgcn_fdot2)
    return __builtin_amdgcn_fdot2(__builtin_bit_cast(f16x2, a),
                                  __builtin_bit_cast(f16x2, b), c, false);
#else
    f16x2 av = __builtin_bit_cast(f16x2, a), bv = __builtin_bit_cast(f16x2, b);
    return c + (float)av[0] * (float)bv[0] + (float)av[1] * (float)bv[1];
#endif
}
__device__ __forceinline__ float rdlf(float v, int lane) {
    return __int_as_float(__builtin_amdgcn_readlane(__float_as_int(v), lane));
}
// lane l <- lane l^1 via DPP quad_perm(1,0,3,2)
__device__ __forceinline__ float dpp_xor1(float v) {
    return __int_as_float(__builtin_amdgcn_update_dpp(
        0, __float_as_int(v), 0xB1, 0xF, 0xF, true));
}
// lanes<32 receive value from lane l+32 (returns operand-1; alias-safe — R10)
__device__ __forceinline__ float perm32hi(float v) {
    int x = __float_as_int(v), y = x;
    asm volatile("v_permlane32_swap_b32 %0, %1" : "+v"(x), "+v"(y));
    return __int_as_float(y);
}
// every lane gets v[l] + v[l^32] (distinct regs forced by v_mov — R11)
__device__ __forceinline__ float swap32_add(float v) {
    int x = __float_as_int(v), y;
    asm volatile("v_mov_b32 %0, %1" : "=v"(y) : "v"(x));
    asm volatile("v_permlane32_swap_b32 %0, %1" : "+v"(x), "+v"(y));
    return __int_as_float(x) + __int_as_float(y);
}
// rotation-reduce over each row of 16, then row_bcast15: lane 16 holds 32-sum
__device__ __forceinline__ float row32_reduce(float v) {
    v += __int_as_float(__builtin_amdgcn_update_dpp(0, __float_as_int(v), 0x121, 0xF, 0xF, true));
    v += __int_as_float(__builtin_amdgcn_update_dpp(0, __float_as_int(v), 0x122, 0xF, 0xF, true));
    v += __int_as_float(__builtin_amdgcn_update_dpp(0, __float_as_int(v), 0x124, 0xF, 0xF, true));
    v += __int_as_float(__builtin_amdgcn_update_dpp(0, __float_as_int(v), 0x128, 0xF, 0xF, true));
    v += __int_as_float(__builtin_amdgcn_update_dpp(0, __float_as_int(v), 0x142, 0xF, 0xF, false));
    return v;
}
__device__ __forceinline__ float sigmoid_f(float x) {
    return RCPF(1.0f + EXP2F(-1.4426950408889634f * x));
}
__device__ __forceinline__ float tanh_f(float x) {
    return __builtin_fmaf(2.0f, RCPF(1.0f + EXP2F(-2.8853900817779268f * x)), -1.0f);
}

// ---------------------------------------------------------------------------
// Kernel 1: blocks 0..191: per-batch static features; block 192: weight pack
// Blob layout v3 (per lane l, m=l&31, h=l>>5):
//  [0..8] wih row l | [9..17] wih2 row 64+m | [18..33] whhp row l
//  [34..49] whh2p row 64+m | [50..65] w1ap row l (cols 0..31)
//  [66..81] w2p row m inputs h*32..+31 | [82..87] W3 COLUMN m (f32, rows 0..5)
//  [90] b_ih[l] [91] b_hh[l] [92] b_ih[64+m] [93] b_hh[64+m] [94] b2[m]
//  [95..100] b3[0..5]
// ---------------------------------------------------------------------------
__global__ __launch_bounds__(1024) void k_static(
    const float* __restrict__ feat,      // (192,32,64,64)
    const float* __restrict__ traj_past, // (192,3,2)
    const float* __restrict__ past_W,    // (32,6)
    const float* __restrict__ past_b,    // (32)
    const float* __restrict__ W1,        // (64,2112)
    const float* __restrict__ b1,        // (64)
    const float* __restrict__ W_ih,      // (96,9)
    const float* __restrict__ W_hh,      // (96,32)
    const float* __restrict__ b_ih,      // (96)
    const float* __restrict__ b_hh,      // (96)
    const float* __restrict__ W2,        // (32,64)
    const float* __restrict__ b2,        // (32)
    const float* __restrict__ W3,        // (6,32)
    const float* __restrict__ b3,        // (6)
    float* __restrict__ ws)
{
    const int b = blockIdx.x;
    const int t = threadIdx.x;

    if (b == NB) {
        if (t >= 64) return;
        const int l = t, m2 = l & 31, h = l >> 5;
        u32* blob = reinterpret_cast<u32*>(ws) + BLOB_F_OFF + (size_t)l * 128;
        #pragma unroll
        for (int k = 0; k < 9; ++k) {
            blob[k]     = __float_as_uint(W_ih[l * 9 + k]);
            blob[9 + k] = __float_as_uint(W_ih[(64 + m2) * 9 + k]);
        }
        #pragma unroll
        for (int j = 0; j < 16; ++j) {
            blob[18 + j] = pk16(W_hh[l * 32 + 2*j],          W_hh[l * 32 + 2*j + 1]);
            blob[34 + j] = pk16(W_hh[(64 + m2) * 32 + 2*j],  W_hh[(64 + m2) * 32 + 2*j + 1]);
            blob[50 + j] = pk16(W1[(size_t)l * 2112 + 2*j],  W1[(size_t)l * 2112 + 2*j + 1]);
        }
        #pragma unroll
        for (int j = 0; j < 16; ++j)
            blob[66 + j] = pk16(W2[m2 * 64 + h * 32 + 2*j], W2[m2 * 64 + h * 32 + 2*j + 1]);
        #pragma unroll
        for (int r = 0; r < 6; ++r)
            blob[82 + r] = __float_as_uint(W3[r * 32 + m2]);   // column m2, f32
        blob[88] = blob[89] = 0u;
        blob[90] = __float_as_uint(b_ih[l]);
        blob[91] = __float_as_uint(b_hh[l]);
        blob[92] = __float_as_uint(b_ih[64 + m2]);
        blob[93] = __float_as_uint(b_hh[64 + m2]);
        blob[94] = __float_as_uint(b2[m2]);
        #pragma unroll
        for (int r = 0; r < 6; ++r) blob[95 + r] = __float_as_uint(b3[r]);
        blob[101] = blob[102] = blob[103] = 0u;
        return;
    }

    __shared__ __align__(16) float sta[2080];

    for (int it = 0; it < 2; ++it) {
        const int c    = it * 16 + (t >> 6);
        const int cell = t & 63;
        const int zi = cell >> 3, xi = cell & 7;
        const float* p = feat + ((size_t)b * NC + c) * 4096 + zi * 8 * 64 + xi * 8;
        float m = -3.402823466e38f;
        #pragma unroll
        for (int dz = 0; dz < 8; ++dz) {
            const float4 v0 = *reinterpret_cast<const float4*>(p + dz * 64);
            const float4 v1 = *reinterpret_cast<const float4*>(p + dz * 64 + 4);
            m = fmaxf(m, fmaxf(fmaxf(fmaxf(v0.x, v0.y), fmaxf(v0.z, v0.w)),
                               fmaxf(fmaxf(v1.x, v1.y), fmaxf(v1.z, v1.w))));
        }
        sta[c * 64 + cell] = m;
    }
    if (t < 32) {
        float acc = past_b[t];
        #pragma unroll
        for (int k = 0; k < 6; ++k) acc += past_W[t * 6 + k] * traj_past[b * 6 + k];
        sta[2048 + t] = acc;
    }
    __syncthreads();

    const int o = t >> 4, l = t & 15;
    const float* wrow = W1 + (size_t)o * 2112 + 32;
    float acc = 0.f;
    #pragma unroll 4
    for (int j = 0; j < 32; ++j) {
        const int k = j * 64 + l * 4;
        const float4 w = *reinterpret_cast<const float4*>(wrow + k);
        const float4 s = *reinterpret_cast<const float4*>(&sta[k]);
        acc += w.x * s.x + w.y * s.y + w.z * s.z + w.w * s.w;
    }
    if (l < 8) {
        const int k = 2048 + l * 4;
        const float4 w = *reinterpret_cast<const float4*>(wrow + k);
        const float4 s = *reinterpret_cast<const float4*>(&sta[k]);
        acc += w.x * s.x + w.y * s.y + w.z * s.z + w.w * s.w;
    }
    acc += __shfl_xor(acc, 1);
    acc += __shfl_xor(acc, 2);
    acc += __shfl_xor(acc, 4);
    acc += __shfl_xor(acc, 8);
    if (l == 0) ws[b * 64 + o] = b1[o] + acc;
}

// ---------------------------------------------------------------------------
// Kernel 2: TWO independent batch recurrences per wave, phase-interleaved so
// each chain's dependent-latency gaps are filled by the other chain, and the
// LDS broadcast round-trips are issued together (latency paid once).
// Weights (dv[26]) are SHARED between the two batches — unlike R6 there are
// no persistent per-batch broadcast copies, so no spills.
// ---------------------------------------------------------------------------
__global__ __launch_bounds__(64, 1) void k_recur(
    const float* __restrict__ pred_map,  // (192,1,64,64)
    const float* __restrict__ noise,     // (192,27,2)
    const float* __restrict__ traj_past, // (192,3,2)
    const float* __restrict__ ws,        // sta1 + blob
    float* __restrict__ out)             // (192,27,2)
{
    __shared__ __align__(16) float pm_0[4096];
    __shared__ __align__(16) float pm_1[4096];
    __shared__ __align__(16) u32 hxbw_0[32], hxbw_1[32];
    __shared__ __align__(16) u32 h1bw_0[32], h1bw_1[32];

    const int l = threadIdx.x;
    const int h = l >> 5;
    const bool odd = (l & 1);
    const int bA = blockIdx.x;
    const int bB = blockIdx.x + NPAIR;

    // ---- stage pred_map for both batches ----
    {
        const float4* s0 = reinterpret_cast<const float4*>(pred_map + (size_t)bA * 4096);
        const float4* s1 = reinterpret_cast<const float4*>(pred_map + (size_t)bB * 4096);
        float4* d0 = reinterpret_cast<float4*>(pm_0);
        float4* d1 = reinterpret_cast<float4*>(pm_1);
        #pragma unroll
        for (int i = 0; i < 16; ++i) { d0[l + i * 64] = s0[l + i * 64]; d1[l + i * 64] = s1[l + i * 64]; }
    }
    const float nz_0 = (l < TFUT * 2) ? noise[bA * (TFUT * 2) + l] : 0.f;
    const float nz_1 = (l < TFUT * 2) ? noise[bB * (TFUT * 2) + l] : 0.f;

    // ---- shared weight blob: 26 x dwordx4 per lane ----
    const u32* blob = reinterpret_cast<const u32*>(ws) + BLOB_F_OFF + (size_t)l * 128;
    u32x4 dv[26];
    #pragma unroll
    for (int j = 0; j < 26; ++j)
        dv[j] = reinterpret_cast<const u32x4*>(blob)[j];
#define DW(i) (dv[(i) >> 2][(i) & 3])
#define DF(i) __int_as_float((int)DW(i))

    const float sta1_0 = ws[bA * 64 + l];
    const float sta1_1 = ws[bB * 64 + l];

    float w_0[6], w_1[6];
    #pragma unroll
    for (int j = 0; j < 6; ++j) { w_0[j] = traj_past[bA * 6 + j]; w_1[j] = traj_past[bB * 6 + j]; }
    float hxp_0 = 0.f, Adot_0 = 0.f, Cdot_0 = 0.f;
    float hxp_1 = 0.f, Adot_1 = 0.f, Cdot_1 = 0.f;

    __syncthreads();

    auto bsamp = [&](const float* pmp, float px, float pz) -> float {
        float x = __builtin_fmaf(2.0f, px, 31.5f);
        float z = __builtin_fmaf(2.0f, pz, 31.5f);
        x = fminf(fmaxf(x, 0.0f), 63.0f);
        z = fminf(fmaxf(z, 0.0f), 63.0f);
        const float xf = floorf(x), zf = floorf(z);
        const int x0 = (int)xf, z0 = (int)zf;
        const int x1 = min(x0 + 1, 63), z1 = min(z0 + 1, 63);
        const float wx = x - xf, wz = z - zf;
        const float v00 = pmp[z0 * 64 + x0], v01 = pmp[z0 * 64 + x1];
        const float v10 = pmp[z1 * 64 + x0], v11 = pmp[z1 * 64 + x1];
        const float top = v00 + wx * (v01 - v00);
        const float bot = v10 + wx * (v11 - v10);
        return top + wz * (bot - top);
    };
    float sm0_0 = bsamp(pm_0, w_0[0], w_0[1]);
    float sm1_0 = bsamp(pm_0, w_0[2], w_0[3]);
    float sm2_0 = bsamp(pm_0, w_0[4], w_0[5]);
    float sm0_1 = bsamp(pm_1, w_1[0], w_1[1]);
    float sm1_1 = bsamp(pm_1, w_1[2], w_1[3]);
    float sm2_1 = bsamp(pm_1, w_1[4], w_1[5]);

    auto pkpair = [&](float v) -> u32 {
        const float nb = dpp_xor1(v);
        const float plo = odd ? nb : v;
        const float phi = odd ? v : nb;
        return pk16(plo, phi);
    };

// ---- phase macros (S = literal suffix; all reg-array indices constant) ----
#define GATES(S) { \
    float giA = DF(90) + DF(3) * w_##S[0] + DF(4) * w_##S[1]; \
    float giB = DF(5) * w_##S[2] + DF(6) * w_##S[3]; \
    float giC = DF(7) * w_##S[4] + DF(8) * w_##S[5]; \
    float giD = DF(0) * sm0_##S + DF(1) * sm1_##S + DF(2) * sm2_##S; \
    const float gi = (giA + giB) + (giC + giD); \
    float gjA = DF(92) + DF(12) * w_##S[0] + DF(13) * w_##S[1]; \
    float gjB = DF(14) * w_##S[2] + DF(15) * w_##S[3]; \
    float gjC = DF(16) * w_##S[4] + DF(17) * w_##S[5]; \
    float gjD = DF(9) * sm0_##S + DF(10) * sm1_##S + DF(11) * sm2_##S; \
    const float gi2 = (gjA + gjB) + (gjC + gjD); \
    const float gs = gi + DF(91) + Adot_##S; \
    const float sg = sigmoid_f(gs); \
    const float zv = perm32hi(sg); \
    const float nv = tanh_f(gi2 + sg * (DF(93) + Cdot_##S)); \
    const float hn = (1.0f - zv) * nv + zv * hxp_##S; \
    hxp_##S = hn; \
    hxbw_##S[l >> 1] = pkpair(hn); }

#define READHX(S) \
    u32 hxpk_##S[16]; \
    { const u32x4* r = reinterpret_cast<const u32x4*>(hxbw_##S); \
      const u32x4 t0 = r[0], t1 = r[1], t2 = r[2], t3 = r[3]; \
      _Pragma("unroll") for (int q = 0; q < 4; ++q) { \
          hxpk_##S[q] = t0[q]; hxpk_##S[4+q] = t1[q]; \
          hxpk_##S[8+q] = t2[q]; hxpk_##S[12+q] = t3[q]; } }

#define H1DOTS(S) \
    float h1l_##S; \
    { float D0 = 0.f, D1 = 0.f, D2 = 0.f, D3 = 0.f; \
      _Pragma("unroll") for (int j = 0; j < 16; j += 4) { \
          D0 = fdot2pk(hxpk_##S[j],   DW(50 + j),     D0); \
          D1 = fdot2pk(hxpk_##S[j+1], DW(50 + j + 1), D1); \
          D2 = fdot2pk(hxpk_##S[j+2], DW(50 + j + 2), D2); \
          D3 = fdot2pk(hxpk_##S[j+3], DW(50 + j + 3), D3); } \
      const float h1a = sta1_##S + ((D0 + D1) + (D2 + D3)); \
      h1l_##S = (h1a >= 0.f) ? h1a : 0.01f * h1a; \
      h1bw_##S[l >> 1] = pkpair(h1l_##S); }

#define READH1(S) \
    u32 h1in_##S[16]; \
    { const u32x4* r = reinterpret_cast<const u32x4*>(h1bw_##S + (h << 4)); \
      const u32x4 t0 = r[0], t1 = r[1], t2 = r[2], t3 = r[3]; \
      _Pragma("unroll") for (int q = 0; q < 4; ++q) { \
          h1in_##S[q] = t0[q]; h1in_##S[4+q] = t1[q]; \
          h1in_##S[8+q] = t2[q]; h1in_##S[12+q] = t3[q]; } }

#define ADCD(S) { \
    float A0 = 0.f, A1 = 0.f, A2 = 0.f, A3 = 0.f; \
    float C0 = 0.f, C1 = 0.f, C2 = 0.f, C3 = 0.f; \
    _Pragma("unroll") for (int j = 0; j < 16; j += 4) { \
        A0 = fdot2pk(hxpk_##S[j],   DW(18 + j),     A0); \
        A1 = fdot2pk(hxpk_##S[j+1], DW(18 + j + 1), A1); \
        A2 = fdot2pk(hxpk_##S[j+2], DW(18 + j + 2), A2); \
        A3 = fdot2pk(hxpk_##S[j+3], DW(18 + j + 3), A3); \
        C0 = fdot2pk(hxpk_##S[j],   DW(34 + j),     C0); \
        C1 = fdot2pk(hxpk_##S[j+1], DW(34 + j + 1), C1); \
        C2 = fdot2pk(hxpk_##S[j+2], DW(34 + j + 2), C2); \
        C3 = fdot2pk(hxpk_##S[j+3], DW(34 + j + 3), C3); } \
    Adot_##S = (A0 + A1) + (A2 + A3); \
    Cdot_##S = (C0 + C1) + (C2 + C3); }

#define TAIL(S, BEXP, PM) { \
    float P0 = 0.f, P1 = 0.f, P2 = 0.f, P3 = 0.f; \
    _Pragma("unroll") for (int j = 0; j < 16; j += 4) { \
        P0 = fdot2pk(h1in_##S[j],   DW(66 + j),     P0); \
        P1 = fdot2pk(h1in_##S[j+1], DW(66 + j + 1), P1); \
        P2 = fdot2pk(h1in_##S[j+2], DW(66 + j + 2), P2); \
        P3 = fdot2pk(h1in_##S[j+3], DW(66 + j + 3), P3); } \
    const float Pown = (P0 + P1) + (P2 + P3); \
    const float h2a = DF(94) + swap32_add(Pown); \
    const float h2l = (h2a >= 0.f) ? h2a : 0.01f * h2a; \
    const float q0 = row32_reduce(DF(82) * h2l); \
    const float q1 = row32_reduce(DF(83) * h2l); \
    const float q2 = row32_reduce(DF(84) * h2l); \
    const float q3 = row32_reduce(DF(85) * h2l); \
    const float q4 = row32_reduce(DF(86) * h2l); \
    const float q5 = row32_reduce(DF(87) * h2l); \
    const float pv0 = rdlf(q0, 16) + DF(95); \
    const float pv1 = rdlf(q1, 16) + DF(96); \
    const float pv2 = rdlf(q2, 16) + DF(97); \
    const float pv3 = rdlf(q3, 16) + DF(98); \
    const float pv4 = rdlf(q4, 16) + DF(99); \
    const float pv5 = rdlf(q5, 16) + DF(100); \
    const float s00 = pv2 + 1e-8f, s01 = pv3; \
    const float s10 = pv4,          s11 = pv5 + 1e-8f; \
    const float p00 = s00 * s00 + s01 * s01; \
    const float p01 = s00 * s10 + s01 * s11; \
    const float p11 = s10 * s10 + s11 * s11; \
    const float nrm = SQRTF(p00 + p11); \
    const float arg = nrm * 0.2f; \
    const float mmx = fmaxf(arg, 1.0f); \
    const float dd  = fabsf(arg - 1.0f); \
    const float den = mmx + 0.6931471805599453f * \
                      LOG2F(1.0f + EXP2F(-1.4426950408889634f * dd)); \
    const float inv  = RCPF(den); \
    const float inv2 = inv * inv; \
    const float nnx = rdlf(nz_##S, 2 * ts); \
    const float nny = rdlf(nz_##S, 2 * ts + 1); \
    const float xd0 = pv0 + nnx * ((p00 + p01) * inv2); \
    const float xd1 = pv1 + nny * ((p01 + p11) * inv2); \
    const float nx0 = 2.0f * w_##S[4] - w_##S[2] + xd0; \
    const float nx1 = 2.0f * w_##S[5] - w_##S[3] + xd1; \
    if (l == 0) { \
        float2 o; o.x = nx0; o.y = nx1; \
        *reinterpret_cast<float2*>(out + ((size_t)(BEXP) * TFUT + ts) * 2) = o; \
    } \
    w_##S[0] = w_##S[2]; w_##S[1] = w_##S[3]; \
    w_##S[2] = w_##S[4]; w_##S[3] = w_##S[5]; \
    w_##S[4] = nx0;      w_##S[5] = nx1; \
    sm0_##S = sm1_##S; sm1_##S = sm2_##S; \
    sm2_##S = bsamp(PM, nx0, nx1); }

    for (int ts = 0; ts < TFUT; ++ts) {
        GATES(0)
        GATES(1)
        LDS_FENCE();
        READHX(0)
        READHX(1)
        H1DOTS(0)
        H1DOTS(1)
        LDS_FENCE();
        READH1(0)
        READH1(1)
        ADCD(0)
        ADCD(1)
        TAIL(0, bA, pm_0)
        TAIL(1, bB, pm_1)
    }
#undef GATES
#undef READHX
#undef H1DOTS
#undef READH1
#undef ADCD
#undef TAIL
#undef DW
#undef DF
}

// ---------------------------------------------------------------------------
extern "C" void kernel_launch(void* const* d_in, const int* in_sizes, int n_in,
                              void* d_out, int out_size, void* d_ws, size_t ws_size,
                              hipStream_t stream) {
    const float* feat      = (const float*)d_in[0];
    const float* pred_map  = (const float*)d_in[1];
    const float* noise     = (const float*)d_in[2];
    const float* traj_past = (const float*)d_in[3];
    const float* W_ih      = (const float*)d_in[4];
    const float* W_hh      = (const float*)d_in[5];
    const float* b_ih      = (const float*)d_in[6];
    const float* b_hh      = (const float*)d_in[7];
    const float* past_W    = (const float*)d_in[8];
    const float* past_b    = (const float*)d_in[9];
    const float* W1        = (const float*)d_in[10];
    const float* b1        = (const float*)d_in[11];
    const float* W2        = (const float*)d_in[12];
    const float* b2        = (const float*)d_in[13];
    const float* W3        = (const float*)d_in[14];
    const float* b3        = (const float*)d_in[15];
    float* outp = (float*)d_out;
    float* ws   = (float*)d_ws;   // sta1 (48 KB) + weight blob (32 KB)

    k_static<<<dim3(NB + 1), dim3(1024), 0, stream>>>(
        feat, traj_past, past_W, past_b, W1, b1,
        W_ih, W_hh, b_ih, b_hh, W2, b2, W3, b3, ws);
    k_recur<<<dim3(NPAIR), dim3(64), 0, stream>>>(pred_map, noise, traj_past, ws, outp);
}

// Round 13
// 45.266 us; speedup vs baseline: 1.3094x; 1.3094x over previous
//
#include <hip/hip_runtime.h>
#include <hip/hip_bf16.h>
#include <math.h>

typedef unsigned int u32;
typedef __fp16 f16x2 __attribute__((ext_vector_type(2)));
typedef u32 u32x4 __attribute__((ext_vector_type(4)));

#define NB    192
#define NC    32
#define TFUT  27
#define BLOB_F_OFF (NB * 64)     // float offset of packed-weight blob inside ws

#if __has_builtin(__builtin_amdgcn_rcpf)
#define RCPF(x) __builtin_amdgcn_rcpf(x)
#else
#define RCPF(x) (1.0f / (x))
#endif
#if __has_builtin(__builtin_amdgcn_sqrtf)
#define SQRTF(x) __builtin_amdgcn_sqrtf(x)
#else
#define SQRTF(x) sqrtf(x)
#endif
#if __has_builtin(__builtin_amdgcn_exp2f)
#define EXP2F(x) __builtin_amdgcn_exp2f(x)
#else
#define EXP2F(x) exp2f(x)
#endif
#if __has_builtin(__builtin_amdgcn_logf)
#define LOG2F(x) __builtin_amdgcn_logf(x)
#else
#define LOG2F(x) log2f(x)
#endif

// compiler-level ordering for intra-wave LDS communication (free at runtime;
// HW DS pipe is in-order within a wave).
#define LDS_FENCE() asm volatile("" ::: "memory")

__device__ __forceinline__ u32 pk16(float lo, float hi) {
    auto v = __builtin_amdgcn_cvt_pkrtz(lo, hi);
    return __builtin_bit_cast(u32, v);
}
__device__ __forceinline__ float fdot2pk(u32 a, u32 b, float c) {
#if __has_builtin(__builtin_amdgcn_fdot2)
    return __builtin_amdgcn_fdot2(__builtin_bit_cast(f16x2, a),
                                  __builtin_bit_cast(f16x2, b), c, false);
#else
    f16x2 av = __builtin_bit_cast(f16x2, a), bv = __builtin_bit_cast(f16x2, b);
    return c + (float)av[0] * (float)bv[0] + (float)av[1] * (float)bv[1];
#endif
}
__device__ __forceinline__ float rdlf(float v, int lane) {
    return __int_as_float(__builtin_amdgcn_readlane(__float_as_int(v), lane));
}
// lane l <- lane l^1 via DPP quad_perm(1,0,3,2)
__device__ __forceinline__ float dpp_xor1(float v) {
    return __int_as_float(__builtin_amdgcn_update_dpp(
        0, __float_as_int(v), 0xB1, 0xF, 0xF, true));
}
// lanes<32 receive value from lane l+32 (returns operand-1; alias-safe — R10)
__device__ __forceinline__ float perm32hi(float v) {
    int x = __float_as_int(v), y = x;
    asm volatile("v_permlane32_swap_b32 %0, %1" : "+v"(x), "+v"(y));
    return __int_as_float(y);
}
// every lane gets v[l] + v[l^32] (distinct regs forced by v_mov — R11)
__device__ __forceinline__ float swap32_add(float v) {
    int x = __float_as_int(v), y;
    asm volatile("v_mov_b32 %0, %1" : "=v"(y) : "v"(x));
    asm volatile("v_permlane32_swap_b32 %0, %1" : "+v"(x), "+v"(y));
    return __int_as_float(x) + __int_as_float(y);
}
// rotation-reduce over each row of 16, then row_bcast15: lanes 16-31 (48-63)
// hold the full 32-lane-group sum (verified on HW in R11, absmax 2.0).
__device__ __forceinline__ float row32_reduce(float v) {
    v += __int_as_float(__builtin_amdgcn_update_dpp(0, __float_as_int(v), 0x121, 0xF, 0xF, true));
    v += __int_as_float(__builtin_amdgcn_update_dpp(0, __float_as_int(v), 0x122, 0xF, 0xF, true));
    v += __int_as_float(__builtin_amdgcn_update_dpp(0, __float_as_int(v), 0x124, 0xF, 0xF, true));
    v += __int_as_float(__builtin_amdgcn_update_dpp(0, __float_as_int(v), 0x128, 0xF, 0xF, true));
    v += __int_as_float(__builtin_amdgcn_update_dpp(0, __float_as_int(v), 0x142, 0xF, 0xF, false));
    return v;
}
__device__ __forceinline__ float sigmoid_f(float x) {
    return RCPF(1.0f + EXP2F(-1.4426950408889634f * x));
}
__device__ __forceinline__ float tanh_f(float x) {
    return __builtin_fmaf(2.0f, RCPF(1.0f + EXP2F(-2.8853900817779268f * x)), -1.0f);
}

// ---------------------------------------------------------------------------
// Kernel 1: blocks 0..191: per-batch static features; block 192: weight pack
// Blob layout v3 (per lane l, m=l&31, h=l>>5):
//  [0..8] wih row l | [9..17] wih2 row 64+m | [18..33] whhp row l
//  [34..49] whh2p row 64+m | [50..65] w1ap row l (cols 0..31)
//  [66..81] w2p row m inputs h*32..+31 | [82..87] W3 COLUMN m (f32, rows 0..5)
//  [90] b_ih[l] [91] b_hh[l] [92] b_ih[64+m] [93] b_hh[64+m] [94] b2[m]
//  [95..100] b3[0..5]
// ---------------------------------------------------------------------------
__global__ __launch_bounds__(1024) void k_static(
    const float* __restrict__ feat,      // (192,32,64,64)
    const float* __restrict__ traj_past, // (192,3,2)
    const float* __restrict__ past_W,    // (32,6)
    const float* __restrict__ past_b,    // (32)
    const float* __restrict__ W1,        // (64,2112)
    const float* __restrict__ b1,        // (64)
    const float* __restrict__ W_ih,      // (96,9)
    const float* __restrict__ W_hh,      // (96,32)
    const float* __restrict__ b_ih,      // (96)
    const float* __restrict__ b_hh,      // (96)
    const float* __restrict__ W2,        // (32,64)
    const float* __restrict__ b2,        // (32)
    const float* __restrict__ W3,        // (6,32)
    const float* __restrict__ b3,        // (6)
    float* __restrict__ ws)
{
    const int b = blockIdx.x;
    const int t = threadIdx.x;

    if (b == NB) {
        if (t >= 64) return;
        const int l = t, m2 = l & 31, h = l >> 5;
        u32* blob = reinterpret_cast<u32*>(ws) + BLOB_F_OFF + (size_t)l * 128;
        #pragma unroll
        for (int k = 0; k < 9; ++k) {
            blob[k]     = __float_as_uint(W_ih[l * 9 + k]);
            blob[9 + k] = __float_as_uint(W_ih[(64 + m2) * 9 + k]);
        }
        #pragma unroll
        for (int j = 0; j < 16; ++j) {
            blob[18 + j] = pk16(W_hh[l * 32 + 2*j],          W_hh[l * 32 + 2*j + 1]);
            blob[34 + j] = pk16(W_hh[(64 + m2) * 32 + 2*j],  W_hh[(64 + m2) * 32 + 2*j + 1]);
            blob[50 + j] = pk16(W1[(size_t)l * 2112 + 2*j],  W1[(size_t)l * 2112 + 2*j + 1]);
        }
        #pragma unroll
        for (int j = 0; j < 16; ++j)
            blob[66 + j] = pk16(W2[m2 * 64 + h * 32 + 2*j], W2[m2 * 64 + h * 32 + 2*j + 1]);
        #pragma unroll
        for (int r = 0; r < 6; ++r)
            blob[82 + r] = __float_as_uint(W3[r * 32 + m2]);   // column m2, f32
        blob[88] = blob[89] = 0u;
        blob[90] = __float_as_uint(b_ih[l]);
        blob[91] = __float_as_uint(b_hh[l]);
        blob[92] = __float_as_uint(b_ih[64 + m2]);
        blob[93] = __float_as_uint(b_hh[64 + m2]);
        blob[94] = __float_as_uint(b2[m2]);
        #pragma unroll
        for (int r = 0; r < 6; ++r) blob[95 + r] = __float_as_uint(b3[r]);
        blob[101] = blob[102] = blob[103] = 0u;
        return;
    }

    __shared__ __align__(16) float sta[2080];

    for (int it = 0; it < 2; ++it) {
        const int c    = it * 16 + (t >> 6);
        const int cell = t & 63;
        const int zi = cell >> 3, xi = cell & 7;
        const float* p = feat + ((size_t)b * NC + c) * 4096 + zi * 8 * 64 + xi * 8;
        float m = -3.402823466e38f;
        #pragma unroll
        for (int dz = 0; dz < 8; ++dz) {
            const float4 v0 = *reinterpret_cast<const float4*>(p + dz * 64);
            const float4 v1 = *reinterpret_cast<const float4*>(p + dz * 64 + 4);
            m = fmaxf(m, fmaxf(fmaxf(fmaxf(v0.x, v0.y), fmaxf(v0.z, v0.w)),
                               fmaxf(fmaxf(v1.x, v1.y), fmaxf(v1.z, v1.w))));
        }
        sta[c * 64 + cell] = m;
    }
    if (t < 32) {
        float acc = past_b[t];
        #pragma unroll
        for (int k = 0; k < 6; ++k) acc += past_W[t * 6 + k] * traj_past[b * 6 + k];
        sta[2048 + t] = acc;
    }
    __syncthreads();

    const int o = t >> 4, l = t & 15;
    const float* wrow = W1 + (size_t)o * 2112 + 32;
    float acc = 0.f;
    #pragma unroll 4
    for (int j = 0; j < 32; ++j) {
        const int k = j * 64 + l * 4;
        const float4 w = *reinterpret_cast<const float4*>(wrow + k);
        const float4 s = *reinterpret_cast<const float4*>(&sta[k]);
        acc += w.x * s.x + w.y * s.y + w.z * s.z + w.w * s.w;
    }
    if (l < 8) {
        const int k = 2048 + l * 4;
        const float4 w = *reinterpret_cast<const float4*>(wrow + k);
        const float4 s = *reinterpret_cast<const float4*>(&sta[k]);
        acc += w.x * s.x + w.y * s.y + w.z * s.z + w.w * s.w;
    }
    acc += __shfl_xor(acc, 1);
    acc += __shfl_xor(acc, 2);
    acc += __shfl_xor(acc, 4);
    acc += __shfl_xor(acc, 8);
    if (l == 0) ws[b * 64 + o] = b1[o] + acc;
}

// ---------------------------------------------------------------------------
// Kernel 2: recurrence. One wave per batch. hx/h1 broadcast via LDS
// round-trip; h2 via permlane32 swap-add; W3 via DPP row-reduce.
// NEW (R13): softclip/Verlet computed LOCALLY on lanes 16-31 (which hold the
// full W3 row sums after row32_reduce) — removes 6 readlane->SGPR hazards
// from the chain; only nx0/nx1 (2 readlanes) are broadcast.
// ---------------------------------------------------------------------------
__global__ __launch_bounds__(64, 1) void k_recur(
    const float* __restrict__ pred_map,  // (192,1,64,64)
    const float* __restrict__ noise,     // (192,27,2)
    const float* __restrict__ traj_past, // (192,3,2)
    const float* __restrict__ ws,        // sta1 + blob
    float* __restrict__ out)             // (192,27,2)
{
    __shared__ __align__(16) float pm[4096];
    __shared__ __align__(16) u32 hxbw[32];   // words 0..15 used
    __shared__ __align__(16) u32 h1bw[32];   // words 0..31

    const int b = blockIdx.x;
    const int l = threadIdx.x;
    const int h = l >> 5;
    const bool odd = (l & 1);

    // ---- stage pred_map into LDS; noise into a lane-resident VGPR ----
    {
        const float4* src = reinterpret_cast<const float4*>(pred_map + (size_t)b * 4096);
        float4* dst = reinterpret_cast<float4*>(pm);
        #pragma unroll
        for (int i = 0; i < 16; ++i) dst[l + i * 64] = src[l + i * 64];
    }
    const float nzreg = (l < TFUT * 2) ? noise[b * (TFUT * 2) + l] : 0.f;

    // ---- coalesced weight-blob load: 26 x dwordx4 per lane ----
    const u32* blob = reinterpret_cast<const u32*>(ws) + BLOB_F_OFF + (size_t)l * 128;
    u32x4 dv[26];
    #pragma unroll
    for (int j = 0; j < 26; ++j)
        dv[j] = reinterpret_cast<const u32x4*>(blob)[j];
#define DW(i) (dv[(i) >> 2][(i) & 3])
#define DF(i) __int_as_float((int)DW(i))

    const float sta1l = ws[b * 64 + l];

    float w[6];
    #pragma unroll
    for (int j = 0; j < 6; ++j) w[j] = traj_past[b * 6 + j];
    float hxp = 0.f;
    float Adot = 0.f, Cdot = 0.f;   // W_hh·hx carried across steps (hx0 = 0)

    __syncthreads();

    auto bsamp = [&](float px, float pz) -> float {
        float x = __builtin_fmaf(2.0f, px, 31.5f);
        float z = __builtin_fmaf(2.0f, pz, 31.5f);
        x = fminf(fmaxf(x, 0.0f), 63.0f);
        z = fminf(fmaxf(z, 0.0f), 63.0f);
        const float xf = floorf(x), zf = floorf(z);
        const int x0 = (int)xf, z0 = (int)zf;
        const int x1 = min(x0 + 1, 63), z1 = min(z0 + 1, 63);
        const float wx = x - xf, wz = z - zf;
        const float v00 = pm[z0 * 64 + x0], v01 = pm[z0 * 64 + x1];
        const float v10 = pm[z1 * 64 + x0], v11 = pm[z1 * 64 + x1];
        const float top = v00 + wx * (v01 - v00);
        const float bot = v10 + wx * (v11 - v10);
        return top + wz * (bot - top);
    };
    float sm0 = bsamp(w[0], w[1]);
    float sm1 = bsamp(w[2], w[3]);
    float sm2 = bsamp(w[4], w[5]);

    // pack-pair helper: both lanes of a pair produce pk16(v_even, v_odd)
    auto pkpair = [&](float v) -> u32 {
        const float nb = dpp_xor1(v);
        const float plo = odd ? nb : v;
        const float phi = odd ? v : nb;
        return pk16(plo, phi);
    };

    for (int ts = 0; ts < TFUT; ++ts) {
        // ---- GATES (window terms first; fresh-sample terms last) ----
        float giA = DF(90) + DF(3) * w[0] + DF(4) * w[1];
        float giB = DF(5) * w[2] + DF(6) * w[3];
        float giC = DF(7) * w[4] + DF(8) * w[5];
        float giD = DF(0) * sm0 + DF(1) * sm1 + DF(2) * sm2;
        const float gi = (giA + giB) + (giC + giD);

        float gjA = DF(92) + DF(12) * w[0] + DF(13) * w[1];
        float gjB = DF(14) * w[2] + DF(15) * w[3];
        float gjC = DF(16) * w[4] + DF(17) * w[5];
        float gjD = DF(9) * sm0 + DF(10) * sm1 + DF(11) * sm2;
        const float gi2 = (gjA + gjB) + (gjC + gjD);

        const float gs = gi + DF(91) + Adot;       // r (l<32) / z (l>=32)
        const float sg = sigmoid_f(gs);
        const float zv = perm32hi(sg);             // z for lanes<32
        const float nv = tanh_f(gi2 + sg * (DF(93) + Cdot));
        const float hn = (1.0f - zv) * nv + zv * hxp;   // valid l<32
        hxp = hn;

        // ---- broadcast hx: write b32 -> fence -> 4x b128 reads ----
        hxbw[l >> 1] = pkpair(hn);
        LDS_FENCE();
        u32 hxpk[16];
        {
            const u32x4* r = reinterpret_cast<const u32x4*>(hxbw);
            const u32x4 t0 = r[0], t1 = r[1], t2 = r[2], t3 = r[3];
            #pragma unroll
            for (int q = 0; q < 4; ++q) {
                hxpk[q]      = t0[q];
                hxpk[4 + q]  = t1[q];
                hxpk[8 + q]  = t2[q];
                hxpk[12 + q] = t3[q];
            }
        }

        // ---- h1 dots only (short critical segment) ----
        float D0 = 0.f, D1 = 0.f, D2 = 0.f, D3 = 0.f;
        #pragma unroll
        for (int j = 0; j < 16; j += 4) {
            D0 = fdot2pk(hxpk[j],   DW(50 + j),     D0);
            D1 = fdot2pk(hxpk[j+1], DW(50 + j + 1), D1);
            D2 = fdot2pk(hxpk[j+2], DW(50 + j + 2), D2);
            D3 = fdot2pk(hxpk[j+3], DW(50 + j + 3), D3);
        }
        const float h1a = sta1l + ((D0 + D1) + (D2 + D3));
        const float h1l = (h1a >= 0.f) ? h1a : 0.01f * h1a;

        // ---- broadcast h1 (own half: 4x b128) ----
        h1bw[l >> 1] = pkpair(h1l);
        LDS_FENCE();
        u32 h1in[16];
        {
            const u32x4* r = reinterpret_cast<const u32x4*>(h1bw + (h << 4));
            const u32x4 t0 = r[0], t1 = r[1], t2 = r[2], t3 = r[3];
            #pragma unroll
            for (int q = 0; q < 4; ++q) {
                h1in[q]      = t0[q];
                h1in[4 + q]  = t1[q];
                h1in[8 + q]  = t2[q];
                h1in[12 + q] = t3[q];
            }
        }

        // ---- Adot + Cdot (next step) in the h1-read shadow ----
        float A0 = 0.f, A1 = 0.f, A2 = 0.f, A3 = 0.f;
        float C0 = 0.f, C1 = 0.f, C2 = 0.f, C3 = 0.f;
        #pragma unroll
        for (int j = 0; j < 16; j += 4) {
            A0 = fdot2pk(hxpk[j],   DW(18 + j),     A0);
            A1 = fdot2pk(hxpk[j+1], DW(18 + j + 1), A1);
            A2 = fdot2pk(hxpk[j+2], DW(18 + j + 2), A2);
            A3 = fdot2pk(hxpk[j+3], DW(18 + j + 3), A3);
            C0 = fdot2pk(hxpk[j],   DW(34 + j),     C0);
            C1 = fdot2pk(hxpk[j+1], DW(34 + j + 1), C1);
            C2 = fdot2pk(hxpk[j+2], DW(34 + j + 2), C2);
            C3 = fdot2pk(hxpk[j+3], DW(34 + j + 3), C3);
        }
        Adot = (A0 + A1) + (A2 + A3);
        Cdot = (C0 + C1) + (C2 + C3);

        // ---- h2: dup-split dot + permlane32 swap-add (valid ALL lanes) ----
        float P0 = 0.f, P1 = 0.f, P2 = 0.f, P3 = 0.f;
        #pragma unroll
        for (int j = 0; j < 16; j += 4) {
            P0 = fdot2pk(h1in[j],   DW(66 + j),     P0);
            P1 = fdot2pk(h1in[j+1], DW(66 + j + 1), P1);
            P2 = fdot2pk(h1in[j+2], DW(66 + j + 2), P2);
            P3 = fdot2pk(h1in[j+3], DW(66 + j + 3), P3);
        }
        const float Pown = (P0 + P1) + (P2 + P3);
        const float h2a = DF(94) + swap32_add(Pown);       // h2[l&31] on every lane
        const float h2l = (h2a >= 0.f) ? h2a : 0.01f * h2a;

        // ---- W3: per-lane column product + DPP row-reduce.
        //      After row32_reduce, lanes 16-31 (48-63) hold the FULL sums. ----
        const float q0 = row32_reduce(DF(82) * h2l);
        const float q1 = row32_reduce(DF(83) * h2l);
        const float q2 = row32_reduce(DF(84) * h2l);
        const float q3 = row32_reduce(DF(85) * h2l);
        const float q4 = row32_reduce(DF(86) * h2l);
        const float q5 = row32_reduce(DF(87) * h2l);

        // ---- pv + softclip + Verlet computed LOCALLY (valid on lanes 16-31;
        //      other lanes compute finite garbage). No readlanes on the chain.
        const float pv0 = q0 + DF(95);
        const float pv1 = q1 + DF(96);
        const float pv2 = q2 + DF(97);
        const float pv3 = q3 + DF(98);
        const float pv4 = q4 + DF(99);
        const float pv5 = q5 + DF(100);

        const float s00 = pv2 + 1e-8f, s01 = pv3;
        const float s10 = pv4,          s11 = pv5 + 1e-8f;
        const float p00 = s00 * s00 + s01 * s01;
        const float p01 = s00 * s10 + s01 * s11;
        const float p11 = s10 * s10 + s11 * s11;
        const float nrm = SQRTF(p00 + p11);
        const float arg = nrm * 0.2f;
        const float mmx = fmaxf(arg, 1.0f);
        const float dd  = fabsf(arg - 1.0f);
        const float den = mmx + 0.6931471805599453f *
                          LOG2F(1.0f + EXP2F(-1.4426950408889634f * dd));
        const float inv  = RCPF(den);
        const float inv2 = inv * inv;

        const float nnx = rdlf(nzreg, 2 * ts);
        const float nny = rdlf(nzreg, 2 * ts + 1);
        const float xd0 = pv0 + nnx * ((p00 + p01) * inv2);
        const float xd1 = pv1 + nny * ((p01 + p11) * inv2);
        const float nx0l = 2.0f * w[4] - w[2] + xd0;   // valid on lanes 16-31
        const float nx1l = 2.0f * w[5] - w[3] + xd1;

        if (l == 16) {
            float2 o; o.x = nx0l; o.y = nx1l;
            *reinterpret_cast<float2*>(out + ((size_t)b * TFUT + ts) * 2) = o;
        }

        // ---- broadcast the 2 scalars that everyone needs ----
        const float nx0 = rdlf(nx0l, 16);
        const float nx1 = rdlf(nx1l, 16);

        w[0] = w[2]; w[1] = w[3];
        w[2] = w[4]; w[3] = w[5];
        w[4] = nx0;  w[5] = nx1;
        sm0 = sm1; sm1 = sm2;
        sm2 = bsamp(nx0, nx1);   // LDS latency hidden by next-iter window FMAs
    }
#undef DW
#undef DF
}

// ---------------------------------------------------------------------------
extern "C" void kernel_launch(void* const* d_in, const int* in_sizes, int n_in,
                              void* d_out, int out_size, void* d_ws, size_t ws_size,
                              hipStream_t stream) {
    const float* feat      = (const float*)d_in[0];
    const float* pred_map  = (const float*)d_in[1];
    const float* noise     = (const float*)d_in[2];
    const float* traj_past = (const float*)d_in[3];
    const float* W_ih      = (const float*)d_in[4];
    const float* W_hh      = (const float*)d_in[5];
    const float* b_ih      = (const float*)d_in[6];
    const float* b_hh      = (const float*)d_in[7];
    const float* past_W    = (const float*)d_in[8];
    const float* past_b    = (const float*)d_in[9];
    const float* W1        = (const float*)d_in[10];
    const float* b1        = (const float*)d_in[11];
    const float* W2        = (const float*)d_in[12];
    const float* b2        = (const float*)d_in[13];
    const float* W3        = (const float*)d_in[14];
    const float* b3        = (const float*)d_in[15];
    float* outp = (float*)d_out;
    float* ws   = (float*)d_ws;   // sta1 (48 KB) + weight blob (32 KB)

    k_static<<<dim3(NB + 1), dim3(1024), 0, stream>>>(
        feat, traj_past, past_W, past_b, W1, b1,
        W_ih, W_hh, b_ih, b_hh, W2, b2, W3, b3, ws);
    k_recur<<<dim3(NB), dim3(64), 0, stream>>>(pred_map, noise, traj_past, ws, outp);
}

// Round 14
// 44.400 us; speedup vs baseline: 1.3349x; 1.0195x over previous
//
#include <hip/hip_runtime.h>
#include <hip/hip_bf16.h>
#include <math.h>

typedef unsigned int u32;
typedef __fp16 f16x2 __attribute__((ext_vector_type(2)));
typedef u32 u32x4 __attribute__((ext_vector_type(4)));

#define NB    192
#define NC    32
#define TFUT  27
#define BLOB_F_OFF (NB * 64)     // float offset of packed-weight blob inside ws

#if __has_builtin(__builtin_amdgcn_rcpf)
#define RCPF(x) __builtin_amdgcn_rcpf(x)
#else
#define RCPF(x) (1.0f / (x))
#endif
#if __has_builtin(__builtin_amdgcn_sqrtf)
#define SQRTF(x) __builtin_amdgcn_sqrtf(x)
#else
#define SQRTF(x) sqrtf(x)
#endif
#if __has_builtin(__builtin_amdgcn_exp2f)
#define EXP2F(x) __builtin_amdgcn_exp2f(x)
#else
#define EXP2F(x) exp2f(x)
#endif
#if __has_builtin(__builtin_amdgcn_logf)
#define LOG2F(x) __builtin_amdgcn_logf(x)
#else
#define LOG2F(x) log2f(x)
#endif

// compiler-level ordering for intra-wave LDS communication (free at runtime;
// HW DS pipe is in-order within a wave).
#define LDS_FENCE() asm volatile("" ::: "memory")

__device__ __forceinline__ u32 pk16(float lo, float hi) {
    auto v = __builtin_amdgcn_cvt_pkrtz(lo, hi);
    return __builtin_bit_cast(u32, v);
}
__device__ __forceinline__ float fdot2pk(u32 a, u32 b, float c) {
#if __has_builtin(__builtin_amdgcn_fdot2)
    return __builtin_amdgcn_fdot2(__builtin_bit_cast(f16x2, a),
                                  __builtin_bit_cast(f16x2, b), c, false);
#else
    f16x2 av = __builtin_bit_cast(f16x2, a), bv = __builtin_bit_cast(f16x2, b);
    return c + (float)av[0] * (float)bv[0] + (float)av[1] * (float)bv[1];
#endif
}
__device__ __forceinline__ float rdlf(float v, int lane) {
    return __int_as_float(__builtin_amdgcn_readlane(__float_as_int(v), lane));
}
// lane l <- lane l^1 via DPP quad_perm(1,0,3,2)
__device__ __forceinline__ float dpp_xor1(float v) {
    return __int_as_float(__builtin_amdgcn_update_dpp(
        0, __float_as_int(v), 0xB1, 0xF, 0xF, true));
}
// lanes<32 receive value from lane l+32 (returns operand-1; alias-safe — R10)
__device__ __forceinline__ float perm32hi(float v) {
    int x = __float_as_int(v), y = x;
    asm volatile("v_permlane32_swap_b32 %0, %1" : "+v"(x), "+v"(y));
    return __int_as_float(y);
}
// every lane gets v[l] + v[l^32] (distinct regs forced by v_mov — R11)
__device__ __forceinline__ float swap32_add(float v) {
    int x = __float_as_int(v), y;
    asm volatile("v_mov_b32 %0, %1" : "=v"(y) : "v"(x));
    asm volatile("v_permlane32_swap_b32 %0, %1" : "+v"(x), "+v"(y));
    return __int_as_float(x) + __int_as_float(y);
}
// rotation-reduce over each row of 16, then row_bcast15: lanes 16-31 (48-63)
// hold the full 32-lane-group sum (verified on HW in R11).
__device__ __forceinline__ float row32_reduce(float v) {
    v += __int_as_float(__builtin_amdgcn_update_dpp(0, __float_as_int(v), 0x121, 0xF, 0xF, true));
    v += __int_as_float(__builtin_amdgcn_update_dpp(0, __float_as_int(v), 0x122, 0xF, 0xF, true));
    v += __int_as_float(__builtin_amdgcn_update_dpp(0, __float_as_int(v), 0x124, 0xF, 0xF, true));
    v += __int_as_float(__builtin_amdgcn_update_dpp(0, __float_as_int(v), 0x128, 0xF, 0xF, true));
    v += __int_as_float(__builtin_amdgcn_update_dpp(0, __float_as_int(v), 0x142, 0xF, 0xF, false));
    return v;
}
__device__ __forceinline__ float sigmoid_f(float x) {
    return RCPF(1.0f + EXP2F(-1.4426950408889634f * x));
}
__device__ __forceinline__ float tanh_f(float x) {
    return __builtin_fmaf(2.0f, RCPF(1.0f + EXP2F(-2.8853900817779268f * x)), -1.0f);
}

// ---------------------------------------------------------------------------
// Kernel 1: blocks 0..191: per-batch static features; block 192: weight pack
// Blob layout v3 (per lane l, m=l&31, h=l>>5):
//  [0..8] wih row l | [9..17] wih2 row 64+m | [18..33] whhp row l
//  [34..49] whh2p row 64+m | [50..65] w1ap row l (cols 0..31)
//  [66..81] w2p row m inputs h*32..+31 | [82..87] W3 COLUMN m (f32, rows 0..5)
//  [90] b_ih[l] [91] b_hh[l] [92] b_ih[64+m] [93] b_hh[64+m] [94] b2[m]
//  [95..100] b3[0..5]
// ---------------------------------------------------------------------------
__global__ __launch_bounds__(1024) void k_static(
    const float* __restrict__ feat,      // (192,32,64,64)
    const float* __restrict__ traj_past, // (192,3,2)
    const float* __restrict__ past_W,    // (32,6)
    const float* __restrict__ past_b,    // (32)
    const float* __restrict__ W1,        // (64,2112)
    const float* __restrict__ b1,        // (64)
    const float* __restrict__ W_ih,      // (96,9)
    const float* __restrict__ W_hh,      // (96,32)
    const float* __restrict__ b_ih,      // (96)
    const float* __restrict__ b_hh,      // (96)
    const float* __restrict__ W2,        // (32,64)
    const float* __restrict__ b2,        // (32)
    const float* __restrict__ W3,        // (6,32)
    const float* __restrict__ b3,        // (6)
    float* __restrict__ ws)
{
    const int b = blockIdx.x;
    const int t = threadIdx.x;

    if (b == NB) {
        if (t >= 64) return;
        const int l = t, m2 = l & 31, h = l >> 5;
        u32* blob = reinterpret_cast<u32*>(ws) + BLOB_F_OFF + (size_t)l * 128;
        #pragma unroll
        for (int k = 0; k < 9; ++k) {
            blob[k]     = __float_as_uint(W_ih[l * 9 + k]);
            blob[9 + k] = __float_as_uint(W_ih[(64 + m2) * 9 + k]);
        }
        #pragma unroll
        for (int j = 0; j < 16; ++j) {
            blob[18 + j] = pk16(W_hh[l * 32 + 2*j],          W_hh[l * 32 + 2*j + 1]);
            blob[34 + j] = pk16(W_hh[(64 + m2) * 32 + 2*j],  W_hh[(64 + m2) * 32 + 2*j + 1]);
            blob[50 + j] = pk16(W1[(size_t)l * 2112 + 2*j],  W1[(size_t)l * 2112 + 2*j + 1]);
        }
        #pragma unroll
        for (int j = 0; j < 16; ++j)
            blob[66 + j] = pk16(W2[m2 * 64 + h * 32 + 2*j], W2[m2 * 64 + h * 32 + 2*j + 1]);
        #pragma unroll
        for (int r = 0; r < 6; ++r)
            blob[82 + r] = __float_as_uint(W3[r * 32 + m2]);   // column m2, f32
        blob[88] = blob[89] = 0u;
        blob[90] = __float_as_uint(b_ih[l]);
        blob[91] = __float_as_uint(b_hh[l]);
        blob[92] = __float_as_uint(b_ih[64 + m2]);
        blob[93] = __float_as_uint(b_hh[64 + m2]);
        blob[94] = __float_as_uint(b2[m2]);
        #pragma unroll
        for (int r = 0; r < 6; ++r) blob[95 + r] = __float_as_uint(b3[r]);
        blob[101] = blob[102] = blob[103] = 0u;
        return;
    }

    __shared__ __align__(16) float sta[2080];

    for (int it = 0; it < 2; ++it) {
        const int c    = it * 16 + (t >> 6);
        const int cell = t & 63;
        const int zi = cell >> 3, xi = cell & 7;
        const float* p = feat + ((size_t)b * NC + c) * 4096 + zi * 8 * 64 + xi * 8;
        float m = -3.402823466e38f;
        #pragma unroll
        for (int dz = 0; dz < 8; ++dz) {
            const float4 v0 = *reinterpret_cast<const float4*>(p + dz * 64);
            const float4 v1 = *reinterpret_cast<const float4*>(p + dz * 64 + 4);
            m = fmaxf(m, fmaxf(fmaxf(fmaxf(v0.x, v0.y), fmaxf(v0.z, v0.w)),
                               fmaxf(fmaxf(v1.x, v1.y), fmaxf(v1.z, v1.w))));
        }
        sta[c * 64 + cell] = m;
    }
    if (t < 32) {
        float acc = past_b[t];
        #pragma unroll
        for (int k = 0; k < 6; ++k) acc += past_W[t * 6 + k] * traj_past[b * 6 + k];
        sta[2048 + t] = acc;
    }
    __syncthreads();

    const int o = t >> 4, l = t & 15;
    const float* wrow = W1 + (size_t)o * 2112 + 32;
    float acc = 0.f;
    #pragma unroll 4
    for (int j = 0; j < 32; ++j) {
        const int k = j * 64 + l * 4;
        const float4 w = *reinterpret_cast<const float4*>(wrow + k);
        const float4 s = *reinterpret_cast<const float4*>(&sta[k]);
        acc += w.x * s.x + w.y * s.y + w.z * s.z + w.w * s.w;
    }
    if (l < 8) {
        const int k = 2048 + l * 4;
        const float4 w = *reinterpret_cast<const float4*>(wrow + k);
        const float4 s = *reinterpret_cast<const float4*>(&sta[k]);
        acc += w.x * s.x + w.y * s.y + w.z * s.z + w.w * s.w;
    }
    acc += __shfl_xor(acc, 1);
    acc += __shfl_xor(acc, 2);
    acc += __shfl_xor(acc, 4);
    acc += __shfl_xor(acc, 8);
    if (l == 0) ws[b * 64 + o] = b1[o] + acc;
}

// ---------------------------------------------------------------------------
// Kernel 2: recurrence. One wave per batch. R10 base (best: 44.6us) plus:
//  - giP/gjP software pipeline: next step's input-gate partials (window w0..3
//    = current w2..5; samples sm0,sm1 = current sm1,sm2) computed in the
//    h1-read shadow -> GATES chain shrinks to ~4 FMAs + Adot.
//  - ADCD split: Adot in h1-read shadow, Cdot in the bsample-read shadow
//    (Cdot is consumed AFTER the sigmoid in next GATES, so it's off-path).
//  - noise readlanes hoisted to step top.
// ---------------------------------------------------------------------------
__global__ __launch_bounds__(64, 1) void k_recur(
    const float* __restrict__ pred_map,  // (192,1,64,64)
    const float* __restrict__ noise,     // (192,27,2)
    const float* __restrict__ traj_past, // (192,3,2)
    const float* __restrict__ ws,        // sta1 + blob
    float* __restrict__ out)             // (192,27,2)
{
    __shared__ __align__(16) float pm[4096];
    __shared__ __align__(16) u32 hxbw[32];   // words 0..15 used
    __shared__ __align__(16) u32 h1bw[32];   // words 0..31

    const int b = blockIdx.x;
    const int l = threadIdx.x;
    const int h = l >> 5;
    const bool odd = (l & 1);

    // ---- stage pred_map into LDS; noise into a lane-resident VGPR ----
    {
        const float4* src = reinterpret_cast<const float4*>(pred_map + (size_t)b * 4096);
        float4* dst = reinterpret_cast<float4*>(pm);
        #pragma unroll
        for (int i = 0; i < 16; ++i) dst[l + i * 64] = src[l + i * 64];
    }
    const float nzreg = (l < TFUT * 2) ? noise[b * (TFUT * 2) + l] : 0.f;

    // ---- coalesced weight-blob load: 26 x dwordx4 per lane ----
    const u32* blob = reinterpret_cast<const u32*>(ws) + BLOB_F_OFF + (size_t)l * 128;
    u32x4 dv[26];
    #pragma unroll
    for (int j = 0; j < 26; ++j)
        dv[j] = reinterpret_cast<const u32x4*>(blob)[j];
#define DW(i) (dv[(i) >> 2][(i) & 3])
#define DF(i) __int_as_float((int)DW(i))

    const float sta1l = ws[b * 64 + l];

    float w[6];
    #pragma unroll
    for (int j = 0; j < 6; ++j) w[j] = traj_past[b * 6 + j];
    float hxp = 0.f;
    float Adot = 0.f, Cdot = 0.f;   // W_hh·hx carried across steps (hx0 = 0)

    __syncthreads();

    auto bsamp = [&](float px, float pz) -> float {
        float x = __builtin_fmaf(2.0f, px, 31.5f);
        float z = __builtin_fmaf(2.0f, pz, 31.5f);
        x = fminf(fmaxf(x, 0.0f), 63.0f);
        z = fminf(fmaxf(z, 0.0f), 63.0f);
        const float xf = floorf(x), zf = floorf(z);
        const int x0 = (int)xf, z0 = (int)zf;
        const int x1 = min(x0 + 1, 63), z1 = min(z0 + 1, 63);
        const float wx = x - xf, wz = z - zf;
        const float v00 = pm[z0 * 64 + x0], v01 = pm[z0 * 64 + x1];
        const float v10 = pm[z1 * 64 + x0], v11 = pm[z1 * 64 + x1];
        const float top = v00 + wx * (v01 - v00);
        const float bot = v10 + wx * (v11 - v10);
        return top + wz * (bot - top);
    };
    float sm0 = bsamp(w[0], w[1]);
    float sm1 = bsamp(w[2], w[3]);
    float sm2 = bsamp(w[4], w[5]);

    // input-gate partials for the FIRST step (terms known before nx/sm2-new)
    float giP = DF(90) + DF(3) * w[0] + DF(4) * w[1] + DF(5) * w[2]
                       + DF(6) * w[3] + DF(0) * sm0 + DF(1) * sm1;
    float gjP = DF(92) + DF(12) * w[0] + DF(13) * w[1] + DF(14) * w[2]
                       + DF(15) * w[3] + DF(9) * sm0 + DF(10) * sm1;

    // pack-pair helper: both lanes of a pair produce pk16(v_even, v_odd)
    auto pkpair = [&](float v) -> u32 {
        const float nb = dpp_xor1(v);
        const float plo = odd ? nb : v;
        const float phi = odd ? v : nb;
        return pk16(plo, phi);
    };

    for (int ts = 0; ts < TFUT; ++ts) {
        // ---- noise broadcast (independent; off the chain) ----
        const float nnx = rdlf(nzreg, 2 * ts);
        const float nny = rdlf(nzreg, 2 * ts + 1);

        // ---- GATES (short: pipelined partials + late terms) ----
        const float gi  = (giP + DF(2) * sm2)  + (DF(7) * w[4] + DF(8) * w[5]);
        const float gi2 = (gjP + DF(11) * sm2) + (DF(16) * w[4] + DF(17) * w[5]);

        const float gs = gi + DF(91) + Adot;       // r (l<32) / z (l>=32)
        const float sg = sigmoid_f(gs);
        const float zv = perm32hi(sg);             // z for lanes<32
        const float nv = tanh_f(gi2 + sg * (DF(93) + Cdot));
        const float hn = __builtin_fmaf(zv, hxp - nv, nv);   // valid l<32
        hxp = hn;

        // ---- broadcast hx: write b32 -> fence -> 4x b128 reads ----
        hxbw[l >> 1] = pkpair(hn);
        LDS_FENCE();
        u32 hxpk[16];
        {
            const u32x4* r = reinterpret_cast<const u32x4*>(hxbw);
            const u32x4 t0 = r[0], t1 = r[1], t2 = r[2], t3 = r[3];
            #pragma unroll
            for (int q = 0; q < 4; ++q) {
                hxpk[q]      = t0[q];
                hxpk[4 + q]  = t1[q];
                hxpk[8 + q]  = t2[q];
                hxpk[12 + q] = t3[q];
            }
        }

        // ---- h1 dots only (short critical segment) ----
        float D0 = 0.f, D1 = 0.f, D2 = 0.f, D3 = 0.f;
        #pragma unroll
        for (int j = 0; j < 16; j += 4) {
            D0 = fdot2pk(hxpk[j],   DW(50 + j),     D0);
            D1 = fdot2pk(hxpk[j+1], DW(50 + j + 1), D1);
            D2 = fdot2pk(hxpk[j+2], DW(50 + j + 2), D2);
            D3 = fdot2pk(hxpk[j+3], DW(50 + j + 3), D3);
        }
        const float h1a = sta1l + ((D0 + D1) + (D2 + D3));
        const float h1l = (h1a >= 0.f) ? h1a : 0.01f * h1a;

        // ---- broadcast h1 (own half: 4x b128) ----
        h1bw[l >> 1] = pkpair(h1l);
        LDS_FENCE();
        u32 h1in[16];
        {
            const u32x4* r = reinterpret_cast<const u32x4*>(h1bw + (h << 4));
            const u32x4 t0 = r[0], t1 = r[1], t2 = r[2], t3 = r[3];
            #pragma unroll
            for (int q = 0; q < 4; ++q) {
                h1in[q]      = t0[q];
                h1in[4 + q]  = t1[q];
                h1in[8 + q]  = t2[q];
                h1in[12 + q] = t3[q];
            }
        }

        // ---- h1-read shadow: Adot (next step) + giP/gjP (next step) ----
        float A0 = 0.f, A1 = 0.f, A2 = 0.f, A3 = 0.f;
        #pragma unroll
        for (int j = 0; j < 16; j += 4) {
            A0 = fdot2pk(hxpk[j],   DW(18 + j),     A0);
            A1 = fdot2pk(hxpk[j+1], DW(18 + j + 1), A1);
            A2 = fdot2pk(hxpk[j+2], DW(18 + j + 2), A2);
            A3 = fdot2pk(hxpk[j+3], DW(18 + j + 3), A3);
        }
        Adot = (A0 + A1) + (A2 + A3);
        // next-iter window terms: next w[0..3] = current w[2..5];
        // next sm0,sm1 = current sm1,sm2 (all known now)
        giP = DF(90) + DF(3) * w[2] + DF(4) * w[3] + DF(5) * w[4]
                     + DF(6) * w[5] + DF(0) * sm1 + DF(1) * sm2;
        gjP = DF(92) + DF(12) * w[2] + DF(13) * w[3] + DF(14) * w[4]
                     + DF(15) * w[5] + DF(9) * sm1 + DF(10) * sm2;

        // ---- h2: dup-split dot + permlane32 swap-add (valid ALL lanes) ----
        float P0 = 0.f, P1 = 0.f, P2 = 0.f, P3 = 0.f;
        #pragma unroll
        for (int j = 0; j < 16; j += 4) {
            P0 = fdot2pk(h1in[j],   DW(66 + j),     P0);
            P1 = fdot2pk(h1in[j+1], DW(66 + j + 1), P1);
            P2 = fdot2pk(h1in[j+2], DW(66 + j + 2), P2);
            P3 = fdot2pk(h1in[j+3], DW(66 + j + 3), P3);
        }
        const float Pown = (P0 + P1) + (P2 + P3);
        const float h2a = DF(94) + swap32_add(Pown);       // h2[l&31] on every lane
        const float h2l = (h2a >= 0.f) ? h2a : 0.01f * h2a;

        // ---- W3: per-lane column product + DPP row-reduce; pv via lane 16 ----
        const float q0 = row32_reduce(DF(82) * h2l);
        const float q1 = row32_reduce(DF(83) * h2l);
        const float q2 = row32_reduce(DF(84) * h2l);
        const float q3 = row32_reduce(DF(85) * h2l);
        const float q4 = row32_reduce(DF(86) * h2l);
        const float q5 = row32_reduce(DF(87) * h2l);

        const float pv0 = rdlf(q0, 16) + DF(95);
        const float pv1 = rdlf(q1, 16) + DF(96);
        const float pv2 = rdlf(q2, 16) + DF(97);
        const float pv3 = rdlf(q3, 16) + DF(98);
        const float pv4 = rdlf(q4, 16) + DF(99);
        const float pv5 = rdlf(q5, 16) + DF(100);

        // ---- softclip (products branch off before the log/exp chain) ----
        const float s00 = pv2 + 1e-8f, s01 = pv3;
        const float s10 = pv4,          s11 = pv5 + 1e-8f;
        const float p00 = s00 * s00 + s01 * s01;
        const float p01 = s00 * s10 + s01 * s11;
        const float p11 = s10 * s10 + s11 * s11;
        const float nrm = SQRTF(p00 + p11);
        const float arg = nrm * 0.2f;
        const float mmx = fmaxf(arg, 1.0f);
        const float dd  = fabsf(arg - 1.0f);
        const float den = mmx + 0.6931471805599453f *
                          LOG2F(1.0f + EXP2F(-1.4426950408889634f * dd));
        const float inv  = RCPF(den);
        const float inv2 = inv * inv;

        const float xd0 = pv0 + nnx * ((p00 + p01) * inv2);
        const float xd1 = pv1 + nny * ((p01 + p11) * inv2);
        const float nx0 = 2.0f * w[4] - w[2] + xd0;
        const float nx1 = 2.0f * w[5] - w[3] + xd1;

        if (l == 0) {
            float2 o; o.x = nx0; o.y = nx1;
            *reinterpret_cast<float2*>(out + ((size_t)b * TFUT + ts) * 2) = o;
        }

        w[0] = w[2]; w[1] = w[3];
        w[2] = w[4]; w[3] = w[5];
        w[4] = nx0;  w[5] = nx1;
        sm0 = sm1; sm1 = sm2;

        // ---- bilinear sample SPLIT: issue the 4 LDS reads... ----
        float v00, v01, v10, v11, wxs, wzs;
        {
            float x = __builtin_fmaf(2.0f, nx0, 31.5f);
            float z = __builtin_fmaf(2.0f, nx1, 31.5f);
            x = fminf(fmaxf(x, 0.0f), 63.0f);
            z = fminf(fmaxf(z, 0.0f), 63.0f);
            const float xf = floorf(x), zf = floorf(z);
            const int x0 = (int)xf, z0 = (int)zf;
            const int x1 = min(x0 + 1, 63), z1 = min(z0 + 1, 63);
            wxs = x - xf; wzs = z - zf;
            v00 = pm[z0 * 64 + x0]; v01 = pm[z0 * 64 + x1];
            v10 = pm[z1 * 64 + x0]; v11 = pm[z1 * 64 + x1];
        }

        // ---- ...fill the bsample latency with next step's Cdot ----
        float C0 = 0.f, C1 = 0.f, C2 = 0.f, C3 = 0.f;
        #pragma unroll
        for (int j = 0; j < 16; j += 4) {
            C0 = fdot2pk(hxpk[j],   DW(34 + j),     C0);
            C1 = fdot2pk(hxpk[j+1], DW(34 + j + 1), C1);
            C2 = fdot2pk(hxpk[j+2], DW(34 + j + 2), C2);
            C3 = fdot2pk(hxpk[j+3], DW(34 + j + 3), C3);
        }
        Cdot = (C0 + C1) + (C2 + C3);

        // ---- finish the interpolation ----
        const float top = v00 + wxs * (v01 - v00);
        const float bot = v10 + wxs * (v11 - v10);
        sm2 = top + wzs * (bot - top);
    }
#undef DW
#undef DF
}

// ---------------------------------------------------------------------------
extern "C" void kernel_launch(void* const* d_in, const int* in_sizes, int n_in,
                              void* d_out, int out_size, void* d_ws, size_t ws_size,
                              hipStream_t stream) {
    const float* feat      = (const float*)d_in[0];
    const float* pred_map  = (const float*)d_in[1];
    const float* noise     = (const float*)d_in[2];
    const float* traj_past = (const float*)d_in[3];
    const float* W_ih      = (const float*)d_in[4];
    const float* W_hh      = (const float*)d_in[5];
    const float* b_ih      = (const float*)d_in[6];
    const float* b_hh      = (const float*)d_in[7];
    const float* past_W    = (const float*)d_in[8];
    const float* past_b    = (const float*)d_in[9];
    const float* W1        = (const float*)d_in[10];
    const float* b1        = (const float*)d_in[11];
    const float* W2        = (const float*)d_in[12];
    const float* b2        = (const float*)d_in[13];
    const float* W3        = (const float*)d_in[14];
    const float* b3        = (const float*)d_in[15];
    float* outp = (float*)d_out;
    float* ws   = (float*)d_ws;   // sta1 (48 KB) + weight blob (32 KB)

    k_static<<<dim3(NB + 1), dim3(1024), 0, stream>>>(
        feat, traj_past, past_W, past_b, W1, b1,
        W_ih, W_hh, b_ih, b_hh, W2, b2, W3, b3, ws);
    k_recur<<<dim3(NB), dim3(64), 0, stream>>>(pred_map, noise, traj_past, ws, outp);
}